// Round 10
// baseline (151.862 us; speedup 1.0000x reference)
//
#include <hip/hip_runtime.h>

typedef unsigned short u16;
typedef __attribute__((ext_vector_type(8))) short short8;
typedef __attribute__((ext_vector_type(8))) __bf16 bf16x8;
typedef __attribute__((ext_vector_type(4))) float f32x4;
typedef __attribute__((ext_vector_type(4))) unsigned int u32x4;

#define MFMA_BF16(a, b, c) __builtin_amdgcn_mfma_f32_16x16x32_bf16((a), (b), (c), 0, 0, 0)

__device__ __forceinline__ u16 f2bf(float f) {
    unsigned u = __builtin_bit_cast(unsigned, f);
    u += 0x7FFFu + ((u >> 16) & 1u);   // round-to-nearest-even; inputs finite
    return (u16)(u >> 16);
}

__device__ __forceinline__ float bf2f(short s) {
    unsigned u = ((unsigned)(u16)s) << 16;
    return __builtin_bit_cast(float, u);
}

// v_cvt_pk_bf16_f32: dst = {bf16(lo), bf16(hi)} packed, RNE
__device__ __forceinline__ unsigned cvt_pk_bf16(float lo, float hi) {
    unsigned r;
    asm("v_cvt_pk_bf16_f32 %0, %1, %2" : "=v"(r) : "v"(lo), "v"(hi));
    return r;
}

// raw v_exp_f32 (exp2); denormal range flushes to 0, which is what we want
__device__ __forceinline__ float fast_exp2(float x) {
    float r;
    asm("v_exp_f32 %0, %1" : "=v"(r) : "v"(x));
    return r;
}

// ---------------------------------------------------------------------------
// Projection GEMM: O[n][c] = bf16( (X[n][:] . W[c][:] + b[c]) * alpha )
// alpha_q = SCALE * log2(e) so attention softmax can use exp2 directly.
// ---------------------------------------------------------------------------
__global__ __launch_bounds__(256) void proj_gemm(
    const float* __restrict__ Xq, const float* __restrict__ Xk, const float* __restrict__ Xv,
    const float* __restrict__ Wq, const float* __restrict__ Wk, const float* __restrict__ Wv,
    const float* __restrict__ bq, const float* __restrict__ bk, const float* __restrict__ bv,
    u16* __restrict__ Oq, u16* __restrict__ Ok, u16* __restrict__ Ov)
{
    constexpr int K = 512, N = 512;
    const int z = blockIdx.z;
    const float* __restrict__ X = (z == 0) ? Xq : (z == 1) ? Xk : Xv;
    const float* __restrict__ W = (z == 0) ? Wq : (z == 1) ? Wk : Wv;
    const float* __restrict__ bias = (z == 0) ? bq : (z == 1) ? bk : bv;
    u16* __restrict__ O = (z == 0) ? Oq : (z == 1) ? Ok : Ov;
    const float alpha = (z == 0) ? 0.125f * 1.44269504088896f : 1.0f;

    __shared__ u16 lA[128 * 64];
    __shared__ u16 lB[128 * 64];

    const int tid = threadIdx.x, lane = tid & 63, w = tid >> 6;
    const int wr = w >> 1, wc = w & 1;
    const int bm = blockIdx.x, bn = blockIdx.y;
    const int r0 = tid >> 3, cc = tid & 7;

    f32x4 acc[4][4];
    for (int m = 0; m < 4; ++m)
        for (int n = 0; n < 4; ++n)
            acc[m][n] = f32x4{0.f, 0.f, 0.f, 0.f};

    for (int kt = 0; kt < K; kt += 64) {
        __syncthreads();
        for (int p = 0; p < 4; ++p) {
            int r = r0 + p * 32;
            {
                const float4* g = (const float4*)(X + (size_t)(bm * 128 + r) * K + kt + cc * 8);
                float4 f0 = g[0], f1 = g[1];
                short8 v;
                v[0] = (short)f2bf(f0.x); v[1] = (short)f2bf(f0.y);
                v[2] = (short)f2bf(f0.z); v[3] = (short)f2bf(f0.w);
                v[4] = (short)f2bf(f1.x); v[5] = (short)f2bf(f1.y);
                v[6] = (short)f2bf(f1.z); v[7] = (short)f2bf(f1.w);
                *(short8*)&lA[r * 64 + ((cc ^ (r & 7)) << 3)] = v;
            }
            {
                const float4* g = (const float4*)(W + (size_t)(bn * 128 + r) * K + kt + cc * 8);
                float4 f0 = g[0], f1 = g[1];
                short8 v;
                v[0] = (short)f2bf(f0.x); v[1] = (short)f2bf(f0.y);
                v[2] = (short)f2bf(f0.z); v[3] = (short)f2bf(f0.w);
                v[4] = (short)f2bf(f1.x); v[5] = (short)f2bf(f1.y);
                v[6] = (short)f2bf(f1.z); v[7] = (short)f2bf(f1.w);
                *(short8*)&lB[r * 64 + ((cc ^ (r & 7)) << 3)] = v;
            }
        }
        __syncthreads();
        for (int kk = 0; kk < 2; ++kk) {
            bf16x8 af[4], bfr[4];
            for (int m = 0; m < 4; ++m) {
                int row = wr * 64 + m * 16 + (lane & 15);
                af[m] = *(const bf16x8*)&lA[row * 64 + (((kk * 4 + (lane >> 4)) ^ (row & 7)) << 3)];
            }
            for (int n = 0; n < 4; ++n) {
                int row = wc * 64 + n * 16 + (lane & 15);
                bfr[n] = *(const bf16x8*)&lB[row * 64 + (((kk * 4 + (lane >> 4)) ^ (row & 7)) << 3)];
            }
            for (int m = 0; m < 4; ++m)
                for (int n = 0; n < 4; ++n)
                    acc[m][n] = MFMA_BF16(af[m], bfr[n], acc[m][n]);
        }
    }
    for (int m = 0; m < 4; ++m)
        for (int n = 0; n < 4; ++n) {
            int row = bm * 128 + wr * 64 + m * 16 + ((lane >> 4) << 2);
            int col = bn * 128 + wc * 64 + n * 16 + (lane & 15);
            float bv_ = bias[col];
            for (int i = 0; i < 4; ++i) {
                float v = (acc[m][n][i] + bv_) * alpha;
                O[(size_t)(row + i) * N + col] = f2bf(v);
            }
        }
}

// ---------------------------------------------------------------------------
// Output GEMM with fused flash-merge of the two KV-half partials:
// A[r][c] = w0*O0[r][c] + w1*O1[r][c],  w_i = l_i*2^{m_i-m} / sum.
// h = kt>>6 is k-tile-uniform (cc*8 < 64), so the ml lookup is per-row only.
// ---------------------------------------------------------------------------
__global__ __launch_bounds__(256) void out_gemm(
    const u16* __restrict__ Op0, const u16* __restrict__ Op1,
    const float2* __restrict__ ml0, const float2* __restrict__ ml1,
    const float* __restrict__ W, const float* __restrict__ bias, float* __restrict__ O)
{
    constexpr int K = 512, N = 512;
    __shared__ u16 lA[128 * 64];
    __shared__ u16 lB[128 * 64];

    const int tid = threadIdx.x, lane = tid & 63, w = tid >> 6;
    const int wr = w >> 1, wc = w & 1;
    const int bm = blockIdx.x, bn = blockIdx.y;
    const int r0 = tid >> 3, cc = tid & 7;

    f32x4 acc[4][4];
    for (int m = 0; m < 4; ++m)
        for (int n = 0; n < 4; ++n)
            acc[m][n] = f32x4{0.f, 0.f, 0.f, 0.f};

    for (int kt = 0; kt < K; kt += 64) {
        const int h = kt >> 6;
        __syncthreads();
        for (int p = 0; p < 4; ++p) {
            int r = r0 + p * 32;
            int grow = bm * 128 + r;
            {
                int mli = (((grow >> 11) * 8 + h) << 11) | (grow & 2047);
                float2 v0 = ml0[mli], v1 = ml1[mli];
                float m = fmaxf(v0.x, v1.x);
                float e0 = exp2f(v0.x - m) * v0.y;
                float e1 = exp2f(v1.x - m) * v1.y;
                float inv = 1.f / (e0 + e1);
                float w0 = e0 * inv, w1 = e1 * inv;
                short8 a0 = *(const short8*)(Op0 + (size_t)grow * K + kt + cc * 8);
                short8 a1 = *(const short8*)(Op1 + (size_t)grow * K + kt + cc * 8);
                short8 v;
                #pragma unroll
                for (int j = 0; j < 8; ++j)
                    v[j] = (short)f2bf(bf2f(a0[j]) * w0 + bf2f(a1[j]) * w1);
                *(short8*)&lA[r * 64 + ((cc ^ (r & 7)) << 3)] = v;
            }
            {
                const float4* g = (const float4*)(W + (size_t)(bn * 128 + r) * K + kt + cc * 8);
                float4 f0 = g[0], f1 = g[1];
                short8 v;
                v[0] = (short)f2bf(f0.x); v[1] = (short)f2bf(f0.y);
                v[2] = (short)f2bf(f0.z); v[3] = (short)f2bf(f0.w);
                v[4] = (short)f2bf(f1.x); v[5] = (short)f2bf(f1.y);
                v[6] = (short)f2bf(f1.z); v[7] = (short)f2bf(f1.w);
                *(short8*)&lB[r * 64 + ((cc ^ (r & 7)) << 3)] = v;
            }
        }
        __syncthreads();
        for (int kk = 0; kk < 2; ++kk) {
            bf16x8 af[4], bfr[4];
            for (int m = 0; m < 4; ++m) {
                int row = wr * 64 + m * 16 + (lane & 15);
                af[m] = *(const bf16x8*)&lA[row * 64 + (((kk * 4 + (lane >> 4)) ^ (row & 7)) << 3)];
            }
            for (int n = 0; n < 4; ++n) {
                int row = wc * 64 + n * 16 + (lane & 15);
                bfr[n] = *(const bf16x8*)&lB[row * 64 + (((kk * 4 + (lane >> 4)) ^ (row & 7)) << 3)];
            }
            for (int m = 0; m < 4; ++m)
                for (int n = 0; n < 4; ++n)
                    acc[m][n] = MFMA_BF16(af[m], bfr[n], acc[m][n]);
        }
    }
    for (int m = 0; m < 4; ++m)
        for (int n = 0; n < 4; ++n) {
            int row = bm * 128 + wr * 64 + m * 16 + ((lane >> 4) << 2);
            int col = bn * 128 + wc * 64 + n * 16 + (lane & 15);
            float bv_ = bias[col];
            for (int i = 0; i < 4; ++i)
                O[(size_t)(row + i) * N + col] = acc[m][n][i] + bv_;
        }
}

// ---------------------------------------------------------------------------
// Flash attention v8: r5's proven two-tile-pairing inner structure, KV split
// ACROSS BLOCKS (z = 0/1, 8 pairs each), single-buffered pair (32 KB LDS,
// 2 barriers/pair). 1024 blocks -> 4 blocks/CU (LDS 128<=160, VGPR<=128 via
// __launch_bounds__(256,4)) = 16 waves/CU, 2x the residency of r5.
// Each block writes a normalized partial O (bf16) + per-row (m,l); the exact
// merge is fused into out_gemm's A-staging.
// ---------------------------------------------------------------------------
__global__ __launch_bounds__(256, 4) void attn_k(
    const u16* __restrict__ Qp, const u16* __restrict__ Kp, const u16* __restrict__ Vp,
    const unsigned char* __restrict__ mask,
    u16* __restrict__ Op0, u16* __restrict__ Op1,
    float2* __restrict__ ml0, float2* __restrict__ ml1)
{
    constexpr int C = 512, NK = 2048, KVH = 1024, NP = KVH / 128;   // 8 pairs
    __shared__ u16 lK[2][64 * 64];   // [tile-in-pair]
    __shared__ u16 lV[2][64 * 64];

    const int tid = threadIdx.x, lane = tid & 63, w = tid >> 6;
    const int gd = lane >> 4, q15 = lane & 15;
    const int bh = blockIdx.x, qb = blockIdx.y, z = blockIdx.z;
    const int b = bh >> 3, h = bh & 7;
    const size_t qrow0 = (size_t)b * 2048 + qb * 64;
    const size_t krow0 = (size_t)b * 2048 + (size_t)z * KVH;
    const int col0 = h * 64;
    const int rs = tid >> 3, cc = tid & 7;

    u16* __restrict__ Op = z ? Op1 : Op0;
    float2* __restrict__ ml = z ? ml1 : ml0;

    // Q fragments in registers (B-operand): lane holds Q[q15][kb*32+gd*8 ..+8]
    bf16x8 qf[2];
    {
        const u16* qrow = Qp + (qrow0 + w * 16 + q15) * C + col0;
        qf[0] = *(const bf16x8*)(qrow + gd * 8);
        qf[1] = *(const bf16x8*)(qrow + 32 + gd * 8);
    }

    float mst = -1e30f, lstp = 0.f;   // running max (row-uniform) / per-lane partial
    f32x4 oacc[4];
    #pragma unroll
    for (int i = 0; i < 4; ++i) oacc[i] = f32x4{0.f, 0.f, 0.f, 0.f};

    // prefetch pair 0
    short8 kreg[2][2], vreg[2][2];
    #pragma unroll
    for (int u = 0; u < 2; ++u)
        #pragma unroll
        for (int p = 0; p < 2; ++p) {
            int r = rs + p * 32;
            kreg[u][p] = *(const short8*)(Kp + (krow0 + u * 64 + r) * C + col0 + cc * 8);
            vreg[u][p] = *(const short8*)(Vp + (krow0 + u * 64 + r) * C + col0 + cc * 8);
        }

    for (int pj = 0; pj < NP; ++pj) {
        __syncthreads();   // previous compute done; safe to overwrite LDS
        #pragma unroll
        for (int u = 0; u < 2; ++u)
            #pragma unroll
            for (int p = 0; p < 2; ++p) {
                int r = rs + p * 32;
                *(short8*)&lK[u][r * 64 + ((cc ^ (r & 7)) << 3)] = kreg[u][p];
                #pragma unroll
                for (int j = 0; j < 8; ++j)
                    lV[u][(cc * 8 + j) * 64 + (((r >> 3) ^ ((j + cc) & 7)) << 3) + (r & 7)] = (u16)vreg[u][p][j];
            }
        // issue next-pair loads (latency hides under the compute phase)
        if (pj + 1 < NP) {
            #pragma unroll
            for (int u = 0; u < 2; ++u)
                #pragma unroll
                for (int p = 0; p < 2; ++p) {
                    const size_t row = krow0 + (pj + 1) * 128 + u * 64 + rs + p * 32;
                    kreg[u][p] = *(const short8*)(Kp + row * C + col0 + cc * 8);
                    vreg[u][p] = *(const short8*)(Vp + row * C + col0 + cc * 8);
                }
        }
        __syncthreads();   // staging visible

        unsigned char mby[2];
        mby[0] = mask[(size_t)b * NK + z * KVH + pj * 128 + lane];
        mby[1] = mask[(size_t)b * NK + z * KVH + pj * 128 + 64 + lane];

        // QK^T for both tiles of the pair
        f32x4 s2[2][4];
        #pragma unroll
        for (int u = 0; u < 2; ++u)
            #pragma unroll
            for (int i = 0; i < 4; ++i) s2[u][i] = f32x4{0.f, 0.f, 0.f, 0.f};
        __builtin_amdgcn_s_setprio(1);
        #pragma unroll
        for (int u = 0; u < 2; ++u) {
            const u16* Kc = &lK[u][0];
            #pragma unroll
            for (int kb = 0; kb < 2; ++kb)
                #pragma unroll
                for (int t4 = 0; t4 < 4; ++t4) {
                    int krow = t4 * 16 + q15;
                    bf16x8 kf = *(const bf16x8*)&Kc[krow * 64 + (((kb * 4 + gd) ^ (krow & 7)) << 3)];
                    s2[u][t4] = MFMA_BF16(kf, qf[kb], s2[u][t4]);
                }
        }
        __builtin_amdgcn_s_setprio(0);

        #pragma unroll
        for (int u = 0; u < 2; ++u) {
            unsigned long long m64 = __ballot(mby[u] != 0);
            if (m64) {
                #pragma unroll
                for (int t4 = 0; t4 < 4; ++t4)
                    #pragma unroll
                    for (int i = 0; i < 4; ++i) {
                        int k = t4 * 16 + gd * 4 + i;
                        if ((m64 >> k) & 1ull) s2[u][t4][i] = -1e30f;
                    }
            }

            float pmax = s2[u][0][0];
            #pragma unroll
            for (int t4 = 0; t4 < 4; ++t4)
                #pragma unroll
                for (int i = 0; i < 4; ++i) pmax = fmaxf(pmax, s2[u][t4][i]);

            if (!__all(pmax - mst <= 11.0f)) {
                float rm = fmaxf(pmax, __shfl_xor(pmax, 16));
                rm = fmaxf(rm, __shfl_xor(rm, 32));
                float mn = fmaxf(mst, rm);
                float sf = exp2f(mst - mn);
                mst = mn;
                lstp *= sf;
                #pragma unroll
                for (int i = 0; i < 4; ++i) {
                    float sfi = __shfl(sf, (lane & 48) | ((gd << 2) + i));
                    #pragma unroll
                    for (int t2 = 0; t2 < 4; ++t2) oacc[t2][i] *= sfi;
                }
            }

            float p[4][4];
            float rsum = 0.f;
            #pragma unroll
            for (int t4 = 0; t4 < 4; ++t4)
                #pragma unroll
                for (int i = 0; i < 4; ++i) {
                    float e = fast_exp2(s2[u][t4][i] - mst);
                    p[t4][i] = e;
                    rsum += e;
                }
            lstp += rsum;   // per-lane partial; reduced once in epilogue

            const u16* Vc = &lV[u][0];
            __builtin_amdgcn_s_setprio(1);
            #pragma unroll
            for (int kb = 0; kb < 2; ++kb) {
                u32x4 pw;
                pw[0] = cvt_pk_bf16(p[2 * kb][0], p[2 * kb][1]);
                pw[1] = cvt_pk_bf16(p[2 * kb][2], p[2 * kb][3]);
                pw[2] = cvt_pk_bf16(p[2 * kb + 1][0], p[2 * kb + 1][1]);
                pw[3] = cvt_pk_bf16(p[2 * kb + 1][2], p[2 * kb + 1][3]);
                bf16x8 pa = __builtin_bit_cast(bf16x8, pw);
                #pragma unroll
                for (int t2 = 0; t2 < 4; ++t2) {
                    int d = t2 * 16 + q15;
                    int swd = (d + (d >> 3)) & 7;
                    int base = d * 64 + 4 * (gd & 1);
                    uint2 v0 = *(const uint2*)&Vc[base + (((4 * kb + 0 + (gd >> 1)) ^ swd) << 3)];
                    uint2 v1 = *(const uint2*)&Vc[base + (((4 * kb + 2 + (gd >> 1)) ^ swd) << 3)];
                    u32x4 vw; vw[0] = v0.x; vw[1] = v0.y; vw[2] = v1.x; vw[3] = v1.y;
                    bf16x8 vf = __builtin_bit_cast(bf16x8, vw);
                    oacc[t2] = MFMA_BF16(pa, vf, oacc[t2]);
                }
            }
            __builtin_amdgcn_s_setprio(0);
        }
    }

    // row-reduce partial sums (lanes sharing q15 across gd groups)
    float lsum = lstp + __shfl_xor(lstp, 16);
    lsum += __shfl_xor(lsum, 32);

    // per-row (m, l) for the merge (one writer per row)
    if (gd == 0)
        ml[bh * 2048 + qb * 64 + w * 16 + q15] = make_float2(mst, lsum);

    // normalized partial O
    #pragma unroll
    for (int i = 0; i < 4; ++i) {
        float li = __shfl(lsum, (lane & 48) | ((gd << 2) + i));
        float inv = 1.f / li;
        int qg = qb * 64 + w * 16 + gd * 4 + i;
        #pragma unroll
        for (int t2 = 0; t2 < 4; ++t2) {
            int col = col0 + t2 * 16 + q15;
            Op[((size_t)b * 2048 + qg) * C + col] = f2bf(oacc[t2][i] * inv);
        }
    }
}

extern "C" void kernel_launch(void* const* d_in, const int* in_sizes, int n_in,
                              void* d_out, int out_size, void* d_ws, size_t ws_size,
                              hipStream_t stream) {
    const float* query = (const float*)d_in[0];
    const float* key   = (const float*)d_in[1];
    const float* value = (const float*)d_in[2];
    const unsigned char* mask = (const unsigned char*)d_in[3];
    const float* Wq = (const float*)d_in[4];
    const float* bq = (const float*)d_in[5];
    const float* Wk = (const float*)d_in[6];
    const float* bk = (const float*)d_in[7];
    const float* Wv = (const float*)d_in[8];
    const float* bv = (const float*)d_in[9];
    const float* Wo = (const float*)d_in[10];
    const float* bo = (const float*)d_in[11];

    // ws layout (u16 units): Qp|Kp|Vp|Op0|Op1 (2M each) then ml0|ml1 (float2)
    u16* ws = (u16*)d_ws;
    u16* Qp  = ws;
    u16* Kp  = ws + 2097152;
    u16* Vp  = ws + 4194304;
    u16* Op0 = ws + 6291456;
    u16* Op1 = ws + 8388608;
    float2* ml0 = (float2*)(ws + 10485760);             // 32768 entries = 256 KB
    float2* ml1 = (float2*)(ws + 10485760 + 131072);    // total ws use ~21.5 MB

    dim3 gp(32, 4, 3);
    proj_gemm<<<gp, 256, 0, stream>>>(query, key, value, Wq, Wk, Wv, bq, bk, bv, Qp, Kp, Vp);

    dim3 ga(16, 32, 2);   // x = bh (XCD locality), y = q-tile, z = KV half
    attn_k<<<ga, 256, 0, stream>>>(Qp, Kp, Vp, mask, Op0, Op1, ml0, ml1);

    dim3 go(32, 4);
    out_gemm<<<go, 256, 0, stream>>>(Op0, Op1, ml0, ml1, Wo, bo, (float*)d_out);
}

// Round 11
// 93.167 us; speedup vs baseline: 1.6300x; 1.6300x over previous
//
#include <hip/hip_runtime.h>

typedef unsigned short u16;
typedef __attribute__((ext_vector_type(8))) short short8;
typedef __attribute__((ext_vector_type(8))) __bf16 bf16x8;
typedef __attribute__((ext_vector_type(4))) float f32x4;
typedef __attribute__((ext_vector_type(4))) unsigned int u32x4;

#define MFMA_BF16(a, b, c) __builtin_amdgcn_mfma_f32_16x16x32_bf16((a), (b), (c), 0, 0, 0)

__device__ __forceinline__ u16 f2bf(float f) {
    unsigned u = __builtin_bit_cast(unsigned, f);
    u += 0x7FFFu + ((u >> 16) & 1u);   // round-to-nearest-even; inputs finite
    return (u16)(u >> 16);
}

__device__ __forceinline__ float bf2f(short s) {
    unsigned u = ((unsigned)(u16)s) << 16;
    return __builtin_bit_cast(float, u);
}

// v_cvt_pk_bf16_f32: dst = {bf16(lo), bf16(hi)} packed, RNE
__device__ __forceinline__ unsigned cvt_pk_bf16(float lo, float hi) {
    unsigned r;
    asm("v_cvt_pk_bf16_f32 %0, %1, %2" : "=v"(r) : "v"(lo), "v"(hi));
    return r;
}

// raw v_exp_f32 (exp2); denormal range flushes to 0, which is what we want
__device__ __forceinline__ float fast_exp2(float x) {
    float r;
    asm("v_exp_f32 %0, %1" : "=v"(r) : "v"(x));
    return r;
}

// ---------------------------------------------------------------------------
// Projection GEMM: O[n][c] = bf16( (X[n][:] . W[c][:] + b[c]) * alpha )
// alpha_q = SCALE * log2(e) so attention softmax can use exp2 directly.
// ---------------------------------------------------------------------------
__global__ __launch_bounds__(256) void proj_gemm(
    const float* __restrict__ Xq, const float* __restrict__ Xk, const float* __restrict__ Xv,
    const float* __restrict__ Wq, const float* __restrict__ Wk, const float* __restrict__ Wv,
    const float* __restrict__ bq, const float* __restrict__ bk, const float* __restrict__ bv,
    u16* __restrict__ Oq, u16* __restrict__ Ok, u16* __restrict__ Ov)
{
    constexpr int K = 512, N = 512;
    const int z = blockIdx.z;
    const float* __restrict__ X = (z == 0) ? Xq : (z == 1) ? Xk : Xv;
    const float* __restrict__ W = (z == 0) ? Wq : (z == 1) ? Wk : Wv;
    const float* __restrict__ bias = (z == 0) ? bq : (z == 1) ? bk : bv;
    u16* __restrict__ O = (z == 0) ? Oq : (z == 1) ? Ok : Ov;
    const float alpha = (z == 0) ? 0.125f * 1.44269504088896f : 1.0f;

    __shared__ u16 lA[128 * 64];
    __shared__ u16 lB[128 * 64];

    const int tid = threadIdx.x, lane = tid & 63, w = tid >> 6;
    const int wr = w >> 1, wc = w & 1;
    const int bm = blockIdx.x, bn = blockIdx.y;
    const int r0 = tid >> 3, cc = tid & 7;

    f32x4 acc[4][4];
    for (int m = 0; m < 4; ++m)
        for (int n = 0; n < 4; ++n)
            acc[m][n] = f32x4{0.f, 0.f, 0.f, 0.f};

    for (int kt = 0; kt < K; kt += 64) {
        __syncthreads();
        for (int p = 0; p < 4; ++p) {
            int r = r0 + p * 32;
            {
                const float4* g = (const float4*)(X + (size_t)(bm * 128 + r) * K + kt + cc * 8);
                float4 f0 = g[0], f1 = g[1];
                short8 v;
                v[0] = (short)f2bf(f0.x); v[1] = (short)f2bf(f0.y);
                v[2] = (short)f2bf(f0.z); v[3] = (short)f2bf(f0.w);
                v[4] = (short)f2bf(f1.x); v[5] = (short)f2bf(f1.y);
                v[6] = (short)f2bf(f1.z); v[7] = (short)f2bf(f1.w);
                *(short8*)&lA[r * 64 + ((cc ^ (r & 7)) << 3)] = v;
            }
            {
                const float4* g = (const float4*)(W + (size_t)(bn * 128 + r) * K + kt + cc * 8);
                float4 f0 = g[0], f1 = g[1];
                short8 v;
                v[0] = (short)f2bf(f0.x); v[1] = (short)f2bf(f0.y);
                v[2] = (short)f2bf(f0.z); v[3] = (short)f2bf(f0.w);
                v[4] = (short)f2bf(f1.x); v[5] = (short)f2bf(f1.y);
                v[6] = (short)f2bf(f1.z); v[7] = (short)f2bf(f1.w);
                *(short8*)&lB[r * 64 + ((cc ^ (r & 7)) << 3)] = v;
            }
        }
        __syncthreads();
        for (int kk = 0; kk < 2; ++kk) {
            bf16x8 af[4], bfr[4];
            for (int m = 0; m < 4; ++m) {
                int row = wr * 64 + m * 16 + (lane & 15);
                af[m] = *(const bf16x8*)&lA[row * 64 + (((kk * 4 + (lane >> 4)) ^ (row & 7)) << 3)];
            }
            for (int n = 0; n < 4; ++n) {
                int row = wc * 64 + n * 16 + (lane & 15);
                bfr[n] = *(const bf16x8*)&lB[row * 64 + (((kk * 4 + (lane >> 4)) ^ (row & 7)) << 3)];
            }
            for (int m = 0; m < 4; ++m)
                for (int n = 0; n < 4; ++n)
                    acc[m][n] = MFMA_BF16(af[m], bfr[n], acc[m][n]);
        }
    }
    for (int m = 0; m < 4; ++m)
        for (int n = 0; n < 4; ++n) {
            int row = bm * 128 + wr * 64 + m * 16 + ((lane >> 4) << 2);
            int col = bn * 128 + wc * 64 + n * 16 + (lane & 15);
            float bv_ = bias[col];
            for (int i = 0; i < 4; ++i) {
                float v = (acc[m][n][i] + bv_) * alpha;
                O[(size_t)(row + i) * N + col] = f2bf(v);
            }
        }
}

// ---------------------------------------------------------------------------
// Output GEMM with fused flash-merge of the two KV-half partials:
// A[r][c] = w0*O0[r][c] + w1*O1[r][c],  w_i = l_i*2^{m_i-m} / sum.
// h = kt>>6 is k-tile-uniform (cc*8 < 64), so the ml lookup is per-row only.
// ---------------------------------------------------------------------------
__global__ __launch_bounds__(256) void out_gemm(
    const u16* __restrict__ Op0, const u16* __restrict__ Op1,
    const float2* __restrict__ ml0, const float2* __restrict__ ml1,
    const float* __restrict__ W, const float* __restrict__ bias, float* __restrict__ O)
{
    constexpr int K = 512, N = 512;
    __shared__ u16 lA[128 * 64];
    __shared__ u16 lB[128 * 64];

    const int tid = threadIdx.x, lane = tid & 63, w = tid >> 6;
    const int wr = w >> 1, wc = w & 1;
    const int bm = blockIdx.x, bn = blockIdx.y;
    const int r0 = tid >> 3, cc = tid & 7;

    f32x4 acc[4][4];
    for (int m = 0; m < 4; ++m)
        for (int n = 0; n < 4; ++n)
            acc[m][n] = f32x4{0.f, 0.f, 0.f, 0.f};

    for (int kt = 0; kt < K; kt += 64) {
        const int h = kt >> 6;
        __syncthreads();
        for (int p = 0; p < 4; ++p) {
            int r = r0 + p * 32;
            int grow = bm * 128 + r;
            {
                int mli = (((grow >> 11) * 8 + h) << 11) | (grow & 2047);
                float2 v0 = ml0[mli], v1 = ml1[mli];
                float m = fmaxf(v0.x, v1.x);
                float e0 = exp2f(v0.x - m) * v0.y;
                float e1 = exp2f(v1.x - m) * v1.y;
                float inv = 1.f / (e0 + e1);
                float w0 = e0 * inv, w1 = e1 * inv;
                short8 a0 = *(const short8*)(Op0 + (size_t)grow * K + kt + cc * 8);
                short8 a1 = *(const short8*)(Op1 + (size_t)grow * K + kt + cc * 8);
                short8 v;
                #pragma unroll
                for (int j = 0; j < 8; ++j)
                    v[j] = (short)f2bf(bf2f(a0[j]) * w0 + bf2f(a1[j]) * w1);
                *(short8*)&lA[r * 64 + ((cc ^ (r & 7)) << 3)] = v;
            }
            {
                const float4* g = (const float4*)(W + (size_t)(bn * 128 + r) * K + kt + cc * 8);
                float4 f0 = g[0], f1 = g[1];
                short8 v;
                v[0] = (short)f2bf(f0.x); v[1] = (short)f2bf(f0.y);
                v[2] = (short)f2bf(f0.z); v[3] = (short)f2bf(f0.w);
                v[4] = (short)f2bf(f1.x); v[5] = (short)f2bf(f1.y);
                v[6] = (short)f2bf(f1.z); v[7] = (short)f2bf(f1.w);
                *(short8*)&lB[r * 64 + ((cc ^ (r & 7)) << 3)] = v;
            }
        }
        __syncthreads();
        for (int kk = 0; kk < 2; ++kk) {
            bf16x8 af[4], bfr[4];
            for (int m = 0; m < 4; ++m) {
                int row = wr * 64 + m * 16 + (lane & 15);
                af[m] = *(const bf16x8*)&lA[row * 64 + (((kk * 4 + (lane >> 4)) ^ (row & 7)) << 3)];
            }
            for (int n = 0; n < 4; ++n) {
                int row = wc * 64 + n * 16 + (lane & 15);
                bfr[n] = *(const bf16x8*)&lB[row * 64 + (((kk * 4 + (lane >> 4)) ^ (row & 7)) << 3)];
            }
            for (int m = 0; m < 4; ++m)
                for (int n = 0; n < 4; ++n)
                    acc[m][n] = MFMA_BF16(af[m], bfr[n], acc[m][n]);
        }
    }
    for (int m = 0; m < 4; ++m)
        for (int n = 0; n < 4; ++n) {
            int row = bm * 128 + wr * 64 + m * 16 + ((lane >> 4) << 2);
            int col = bn * 128 + wc * 64 + n * 16 + (lane & 15);
            float bv_ = bias[col];
            for (int i = 0; i < 4; ++i)
                O[(size_t)(row + i) * N + col] = acc[m][n][i] + bv_;
        }
}

// ---------------------------------------------------------------------------
// Flash attention v8b: identical to round 10 EXCEPT __launch_bounds__(256, 2).
// Empirical rule from rounds 5-10: effective VGPR cap = 512/(2*arg); arg=4
// forced 64 VGPR and massive spills (r6, r10). arg=2 -> cap 128; this inner
// structure needs ~124 (r5 measurement) -> no spill, and 4 blocks/CU remain
// possible via the LDS gate (4 x 32 KB = 128 <= 160 KB) with grid 1024.
// ---------------------------------------------------------------------------
__global__ __launch_bounds__(256, 2) void attn_k(
    const u16* __restrict__ Qp, const u16* __restrict__ Kp, const u16* __restrict__ Vp,
    const unsigned char* __restrict__ mask,
    u16* __restrict__ Op0, u16* __restrict__ Op1,
    float2* __restrict__ ml0, float2* __restrict__ ml1)
{
    constexpr int C = 512, NK = 2048, KVH = 1024, NP = KVH / 128;   // 8 pairs
    __shared__ u16 lK[2][64 * 64];   // [tile-in-pair]
    __shared__ u16 lV[2][64 * 64];

    const int tid = threadIdx.x, lane = tid & 63, w = tid >> 6;
    const int gd = lane >> 4, q15 = lane & 15;
    const int bh = blockIdx.x, qb = blockIdx.y, z = blockIdx.z;
    const int b = bh >> 3, h = bh & 7;
    const size_t qrow0 = (size_t)b * 2048 + qb * 64;
    const size_t krow0 = (size_t)b * 2048 + (size_t)z * KVH;
    const int col0 = h * 64;
    const int rs = tid >> 3, cc = tid & 7;

    u16* __restrict__ Op = z ? Op1 : Op0;
    float2* __restrict__ ml = z ? ml1 : ml0;

    // Q fragments in registers (B-operand): lane holds Q[q15][kb*32+gd*8 ..+8]
    bf16x8 qf[2];
    {
        const u16* qrow = Qp + (qrow0 + w * 16 + q15) * C + col0;
        qf[0] = *(const bf16x8*)(qrow + gd * 8);
        qf[1] = *(const bf16x8*)(qrow + 32 + gd * 8);
    }

    float mst = -1e30f, lstp = 0.f;   // running max (row-uniform) / per-lane partial
    f32x4 oacc[4];
    #pragma unroll
    for (int i = 0; i < 4; ++i) oacc[i] = f32x4{0.f, 0.f, 0.f, 0.f};

    // prefetch pair 0
    short8 kreg[2][2], vreg[2][2];
    #pragma unroll
    for (int u = 0; u < 2; ++u)
        #pragma unroll
        for (int p = 0; p < 2; ++p) {
            int r = rs + p * 32;
            kreg[u][p] = *(const short8*)(Kp + (krow0 + u * 64 + r) * C + col0 + cc * 8);
            vreg[u][p] = *(const short8*)(Vp + (krow0 + u * 64 + r) * C + col0 + cc * 8);
        }

    for (int pj = 0; pj < NP; ++pj) {
        __syncthreads();   // previous compute done; safe to overwrite LDS
        #pragma unroll
        for (int u = 0; u < 2; ++u)
            #pragma unroll
            for (int p = 0; p < 2; ++p) {
                int r = rs + p * 32;
                *(short8*)&lK[u][r * 64 + ((cc ^ (r & 7)) << 3)] = kreg[u][p];
                #pragma unroll
                for (int j = 0; j < 8; ++j)
                    lV[u][(cc * 8 + j) * 64 + (((r >> 3) ^ ((j + cc) & 7)) << 3) + (r & 7)] = (u16)vreg[u][p][j];
            }
        // issue next-pair loads (latency hides under the compute phase)
        if (pj + 1 < NP) {
            #pragma unroll
            for (int u = 0; u < 2; ++u)
                #pragma unroll
                for (int p = 0; p < 2; ++p) {
                    const size_t row = krow0 + (pj + 1) * 128 + u * 64 + rs + p * 32;
                    kreg[u][p] = *(const short8*)(Kp + row * C + col0 + cc * 8);
                    vreg[u][p] = *(const short8*)(Vp + row * C + col0 + cc * 8);
                }
        }
        __syncthreads();   // staging visible

        unsigned char mby[2];
        mby[0] = mask[(size_t)b * NK + z * KVH + pj * 128 + lane];
        mby[1] = mask[(size_t)b * NK + z * KVH + pj * 128 + 64 + lane];

        // QK^T for both tiles of the pair
        f32x4 s2[2][4];
        #pragma unroll
        for (int u = 0; u < 2; ++u)
            #pragma unroll
            for (int i = 0; i < 4; ++i) s2[u][i] = f32x4{0.f, 0.f, 0.f, 0.f};
        __builtin_amdgcn_s_setprio(1);
        #pragma unroll
        for (int u = 0; u < 2; ++u) {
            const u16* Kc = &lK[u][0];
            #pragma unroll
            for (int kb = 0; kb < 2; ++kb)
                #pragma unroll
                for (int t4 = 0; t4 < 4; ++t4) {
                    int krow = t4 * 16 + q15;
                    bf16x8 kf = *(const bf16x8*)&Kc[krow * 64 + (((kb * 4 + gd) ^ (krow & 7)) << 3)];
                    s2[u][t4] = MFMA_BF16(kf, qf[kb], s2[u][t4]);
                }
        }
        __builtin_amdgcn_s_setprio(0);

        #pragma unroll
        for (int u = 0; u < 2; ++u) {
            unsigned long long m64 = __ballot(mby[u] != 0);
            if (m64) {
                #pragma unroll
                for (int t4 = 0; t4 < 4; ++t4)
                    #pragma unroll
                    for (int i = 0; i < 4; ++i) {
                        int k = t4 * 16 + gd * 4 + i;
                        if ((m64 >> k) & 1ull) s2[u][t4][i] = -1e30f;
                    }
            }

            float pmax = s2[u][0][0];
            #pragma unroll
            for (int t4 = 0; t4 < 4; ++t4)
                #pragma unroll
                for (int i = 0; i < 4; ++i) pmax = fmaxf(pmax, s2[u][t4][i]);

            if (!__all(pmax - mst <= 11.0f)) {
                float rm = fmaxf(pmax, __shfl_xor(pmax, 16));
                rm = fmaxf(rm, __shfl_xor(rm, 32));
                float mn = fmaxf(mst, rm);
                float sf = exp2f(mst - mn);
                mst = mn;
                lstp *= sf;
                #pragma unroll
                for (int i = 0; i < 4; ++i) {
                    float sfi = __shfl(sf, (lane & 48) | ((gd << 2) + i));
                    #pragma unroll
                    for (int t2 = 0; t2 < 4; ++t2) oacc[t2][i] *= sfi;
                }
            }

            float p[4][4];
            float rsum = 0.f;
            #pragma unroll
            for (int t4 = 0; t4 < 4; ++t4)
                #pragma unroll
                for (int i = 0; i < 4; ++i) {
                    float e = fast_exp2(s2[u][t4][i] - mst);
                    p[t4][i] = e;
                    rsum += e;
                }
            lstp += rsum;   // per-lane partial; reduced once in epilogue

            const u16* Vc = &lV[u][0];
            __builtin_amdgcn_s_setprio(1);
            #pragma unroll
            for (int kb = 0; kb < 2; ++kb) {
                u32x4 pw;
                pw[0] = cvt_pk_bf16(p[2 * kb][0], p[2 * kb][1]);
                pw[1] = cvt_pk_bf16(p[2 * kb][2], p[2 * kb][3]);
                pw[2] = cvt_pk_bf16(p[2 * kb + 1][0], p[2 * kb + 1][1]);
                pw[3] = cvt_pk_bf16(p[2 * kb + 1][2], p[2 * kb + 1][3]);
                bf16x8 pa = __builtin_bit_cast(bf16x8, pw);
                #pragma unroll
                for (int t2 = 0; t2 < 4; ++t2) {
                    int d = t2 * 16 + q15;
                    int swd = (d + (d >> 3)) & 7;
                    int base = d * 64 + 4 * (gd & 1);
                    uint2 v0 = *(const uint2*)&Vc[base + (((4 * kb + 0 + (gd >> 1)) ^ swd) << 3)];
                    uint2 v1 = *(const uint2*)&Vc[base + (((4 * kb + 2 + (gd >> 1)) ^ swd) << 3)];
                    u32x4 vw; vw[0] = v0.x; vw[1] = v0.y; vw[2] = v1.x; vw[3] = v1.y;
                    bf16x8 vf = __builtin_bit_cast(bf16x8, vw);
                    oacc[t2] = MFMA_BF16(pa, vf, oacc[t2]);
                }
            }
            __builtin_amdgcn_s_setprio(0);
        }
    }

    // row-reduce partial sums (lanes sharing q15 across gd groups)
    float lsum = lstp + __shfl_xor(lstp, 16);
    lsum += __shfl_xor(lsum, 32);

    // per-row (m, l) for the merge (one writer per row)
    if (gd == 0)
        ml[bh * 2048 + qb * 64 + w * 16 + q15] = make_float2(mst, lsum);

    // normalized partial O
    #pragma unroll
    for (int i = 0; i < 4; ++i) {
        float li = __shfl(lsum, (lane & 48) | ((gd << 2) + i));
        float inv = 1.f / li;
        int qg = qb * 64 + w * 16 + gd * 4 + i;
        #pragma unroll
        for (int t2 = 0; t2 < 4; ++t2) {
            int col = col0 + t2 * 16 + q15;
            Op[((size_t)b * 2048 + qg) * C + col] = f2bf(oacc[t2][i] * inv);
        }
    }
}

extern "C" void kernel_launch(void* const* d_in, const int* in_sizes, int n_in,
                              void* d_out, int out_size, void* d_ws, size_t ws_size,
                              hipStream_t stream) {
    const float* query = (const float*)d_in[0];
    const float* key   = (const float*)d_in[1];
    const float* value = (const float*)d_in[2];
    const unsigned char* mask = (const unsigned char*)d_in[3];
    const float* Wq = (const float*)d_in[4];
    const float* bq = (const float*)d_in[5];
    const float* Wk = (const float*)d_in[6];
    const float* bk = (const float*)d_in[7];
    const float* Wv = (const float*)d_in[8];
    const float* bv = (const float*)d_in[9];
    const float* Wo = (const float*)d_in[10];
    const float* bo = (const float*)d_in[11];

    // ws layout (u16 units): Qp|Kp|Vp|Op0|Op1 (2M each) then ml0|ml1 (float2)
    u16* ws = (u16*)d_ws;
    u16* Qp  = ws;
    u16* Kp  = ws + 2097152;
    u16* Vp  = ws + 4194304;
    u16* Op0 = ws + 6291456;
    u16* Op1 = ws + 8388608;
    float2* ml0 = (float2*)(ws + 10485760);             // 32768 entries = 256 KB
    float2* ml1 = (float2*)(ws + 10485760 + 131072);    // total ws use ~21.5 MB

    dim3 gp(32, 4, 3);
    proj_gemm<<<gp, 256, 0, stream>>>(query, key, value, Wq, Wk, Wv, bq, bk, bv, Qp, Kp, Vp);

    dim3 ga(16, 32, 2);   // x = bh (XCD locality), y = q-tile, z = KV half
    attn_k<<<ga, 256, 0, stream>>>(Qp, Kp, Vp, mask, Op0, Op1, ml0, ml1);

    dim3 go(32, 4);
    out_gemm<<<go, 256, 0, stream>>>(Op0, Op1, ml0, ml1, Wo, bo, (float*)d_out);
}

// Round 12
// 77.135 us; speedup vs baseline: 1.9688x; 1.2079x over previous
//
#include <hip/hip_runtime.h>

typedef unsigned short u16;
typedef __attribute__((ext_vector_type(8))) short short8;
typedef __attribute__((ext_vector_type(8))) __bf16 bf16x8;
typedef __attribute__((ext_vector_type(4))) float f32x4;
typedef __attribute__((ext_vector_type(4))) unsigned int u32x4;

#define MFMA_BF16(a, b, c) __builtin_amdgcn_mfma_f32_16x16x32_bf16((a), (b), (c), 0, 0, 0)

__device__ __forceinline__ u16 f2bf(float f) {
    unsigned u = __builtin_bit_cast(unsigned, f);
    u += 0x7FFFu + ((u >> 16) & 1u);   // round-to-nearest-even; inputs finite
    return (u16)(u >> 16);
}

__device__ __forceinline__ float bf2f(short s) {
    unsigned u = ((unsigned)(u16)s) << 16;
    return __builtin_bit_cast(float, u);
}

// v_cvt_pk_bf16_f32: dst = {bf16(lo), bf16(hi)} packed, RNE
__device__ __forceinline__ unsigned cvt_pk_bf16(float lo, float hi) {
    unsigned r;
    asm("v_cvt_pk_bf16_f32 %0, %1, %2" : "=v"(r) : "v"(lo), "v"(hi));
    return r;
}

// raw v_exp_f32 (exp2); denormal range flushes to 0, which is what we want
__device__ __forceinline__ float fast_exp2(float x) {
    float r;
    asm("v_exp_f32 %0, %1" : "=v"(r) : "v"(x));
    return r;
}

// ---------------------------------------------------------------------------
// Projection GEMM: O[n][c] = bf16( (X[n][:] . W[c][:] + b[c]) * alpha )
// alpha_q = SCALE * log2(e) so attention softmax can use exp2 directly.
// ---------------------------------------------------------------------------
__global__ __launch_bounds__(256) void proj_gemm(
    const float* __restrict__ Xq, const float* __restrict__ Xk, const float* __restrict__ Xv,
    const float* __restrict__ Wq, const float* __restrict__ Wk, const float* __restrict__ Wv,
    const float* __restrict__ bq, const float* __restrict__ bk, const float* __restrict__ bv,
    u16* __restrict__ Oq, u16* __restrict__ Ok, u16* __restrict__ Ov)
{
    constexpr int K = 512, N = 512;
    const int z = blockIdx.z;
    const float* __restrict__ X = (z == 0) ? Xq : (z == 1) ? Xk : Xv;
    const float* __restrict__ W = (z == 0) ? Wq : (z == 1) ? Wk : Wv;
    const float* __restrict__ bias = (z == 0) ? bq : (z == 1) ? bk : bv;
    u16* __restrict__ O = (z == 0) ? Oq : (z == 1) ? Ok : Ov;
    const float alpha = (z == 0) ? 0.125f * 1.44269504088896f : 1.0f;

    __shared__ u16 lA[128 * 64];
    __shared__ u16 lB[128 * 64];

    const int tid = threadIdx.x, lane = tid & 63, w = tid >> 6;
    const int wr = w >> 1, wc = w & 1;
    const int bm = blockIdx.x, bn = blockIdx.y;
    const int r0 = tid >> 3, cc = tid & 7;

    f32x4 acc[4][4];
    for (int m = 0; m < 4; ++m)
        for (int n = 0; n < 4; ++n)
            acc[m][n] = f32x4{0.f, 0.f, 0.f, 0.f};

    for (int kt = 0; kt < K; kt += 64) {
        __syncthreads();
        for (int p = 0; p < 4; ++p) {
            int r = r0 + p * 32;
            {
                const float4* g = (const float4*)(X + (size_t)(bm * 128 + r) * K + kt + cc * 8);
                float4 f0 = g[0], f1 = g[1];
                short8 v;
                v[0] = (short)f2bf(f0.x); v[1] = (short)f2bf(f0.y);
                v[2] = (short)f2bf(f0.z); v[3] = (short)f2bf(f0.w);
                v[4] = (short)f2bf(f1.x); v[5] = (short)f2bf(f1.y);
                v[6] = (short)f2bf(f1.z); v[7] = (short)f2bf(f1.w);
                *(short8*)&lA[r * 64 + ((cc ^ (r & 7)) << 3)] = v;
            }
            {
                const float4* g = (const float4*)(W + (size_t)(bn * 128 + r) * K + kt + cc * 8);
                float4 f0 = g[0], f1 = g[1];
                short8 v;
                v[0] = (short)f2bf(f0.x); v[1] = (short)f2bf(f0.y);
                v[2] = (short)f2bf(f0.z); v[3] = (short)f2bf(f0.w);
                v[4] = (short)f2bf(f1.x); v[5] = (short)f2bf(f1.y);
                v[6] = (short)f2bf(f1.z); v[7] = (short)f2bf(f1.w);
                *(short8*)&lB[r * 64 + ((cc ^ (r & 7)) << 3)] = v;
            }
        }
        __syncthreads();
        for (int kk = 0; kk < 2; ++kk) {
            bf16x8 af[4], bfr[4];
            for (int m = 0; m < 4; ++m) {
                int row = wr * 64 + m * 16 + (lane & 15);
                af[m] = *(const bf16x8*)&lA[row * 64 + (((kk * 4 + (lane >> 4)) ^ (row & 7)) << 3)];
            }
            for (int n = 0; n < 4; ++n) {
                int row = wc * 64 + n * 16 + (lane & 15);
                bfr[n] = *(const bf16x8*)&lB[row * 64 + (((kk * 4 + (lane >> 4)) ^ (row & 7)) << 3)];
            }
            for (int m = 0; m < 4; ++m)
                for (int n = 0; n < 4; ++n)
                    acc[m][n] = MFMA_BF16(af[m], bfr[n], acc[m][n]);
        }
    }
    for (int m = 0; m < 4; ++m)
        for (int n = 0; n < 4; ++n) {
            int row = bm * 128 + wr * 64 + m * 16 + ((lane >> 4) << 2);
            int col = bn * 128 + wc * 64 + n * 16 + (lane & 15);
            float bv_ = bias[col];
            for (int i = 0; i < 4; ++i) {
                float v = (acc[m][n][i] + bv_) * alpha;
                O[(size_t)(row + i) * N + col] = f2bf(v);
            }
        }
}

// ---------------------------------------------------------------------------
// Merge kernel: Ob = w0*O0 + w1*O1, wi = li*2^(mi-m)/sum (exact flash merge).
// Pure streaming: 1024 blocks x 256 threads, one short8 per thread.
// ---------------------------------------------------------------------------
__global__ __launch_bounds__(256) void merge_k(
    const u16* __restrict__ Op0, const u16* __restrict__ Op1,
    const float2* __restrict__ ml0, const float2* __restrict__ ml1,
    u16* __restrict__ Ob)
{
    int idx = blockIdx.x * 256 + threadIdx.x;   // 0 .. 262143 (4096 rows x 64 chunks)
    int row = idx >> 6;
    int c8 = idx & 63;
    int h = c8 >> 3;
    int b = row >> 11;
    int mli = (b * 8 + h) * 2048 + (row & 2047);
    float2 v0 = ml0[mli], v1 = ml1[mli];
    float m = fmaxf(v0.x, v1.x);
    float e0 = exp2f(v0.x - m) * v0.y;
    float e1 = exp2f(v1.x - m) * v1.y;
    float inv = 1.f / (e0 + e1);
    float w0 = e0 * inv, w1 = e1 * inv;
    size_t off = (size_t)row * 512 + c8 * 8;
    short8 a0 = *(const short8*)(Op0 + off);
    short8 a1 = *(const short8*)(Op1 + off);
    short8 v;
    #pragma unroll
    for (int j = 0; j < 8; ++j)
        v[j] = (short)f2bf(bf2f(a0[j]) * w0 + bf2f(a1[j]) * w1);
    *(short8*)(Ob + off) = v;
}

// ---------------------------------------------------------------------------
// Output GEMM (r5-proven version: plain bf16 A input)
// ---------------------------------------------------------------------------
__global__ __launch_bounds__(256) void out_gemm(
    const u16* __restrict__ A, const float* __restrict__ W,
    const float* __restrict__ bias, float* __restrict__ O)
{
    constexpr int K = 512, N = 512;
    __shared__ u16 lA[128 * 64];
    __shared__ u16 lB[128 * 64];

    const int tid = threadIdx.x, lane = tid & 63, w = tid >> 6;
    const int wr = w >> 1, wc = w & 1;
    const int bm = blockIdx.x, bn = blockIdx.y;
    const int r0 = tid >> 3, cc = tid & 7;

    f32x4 acc[4][4];
    for (int m = 0; m < 4; ++m)
        for (int n = 0; n < 4; ++n)
            acc[m][n] = f32x4{0.f, 0.f, 0.f, 0.f};

    for (int kt = 0; kt < K; kt += 64) {
        __syncthreads();
        for (int p = 0; p < 4; ++p) {
            int r = r0 + p * 32;
            *(short8*)&lA[r * 64 + ((cc ^ (r & 7)) << 3)] =
                *(const short8*)(A + (size_t)(bm * 128 + r) * K + kt + cc * 8);
            const float4* g = (const float4*)(W + (size_t)(bn * 128 + r) * K + kt + cc * 8);
            float4 f0 = g[0], f1 = g[1];
            short8 v;
            v[0] = (short)f2bf(f0.x); v[1] = (short)f2bf(f0.y);
            v[2] = (short)f2bf(f0.z); v[3] = (short)f2bf(f0.w);
            v[4] = (short)f2bf(f1.x); v[5] = (short)f2bf(f1.y);
            v[6] = (short)f2bf(f1.z); v[7] = (short)f2bf(f1.w);
            *(short8*)&lB[r * 64 + ((cc ^ (r & 7)) << 3)] = v;
        }
        __syncthreads();
        for (int kk = 0; kk < 2; ++kk) {
            bf16x8 af[4], bfr[4];
            for (int m = 0; m < 4; ++m) {
                int row = wr * 64 + m * 16 + (lane & 15);
                af[m] = *(const bf16x8*)&lA[row * 64 + (((kk * 4 + (lane >> 4)) ^ (row & 7)) << 3)];
            }
            for (int n = 0; n < 4; ++n) {
                int row = wc * 64 + n * 16 + (lane & 15);
                bfr[n] = *(const bf16x8*)&lB[row * 64 + (((kk * 4 + (lane >> 4)) ^ (row & 7)) << 3)];
            }
            for (int m = 0; m < 4; ++m)
                for (int n = 0; n < 4; ++n)
                    acc[m][n] = MFMA_BF16(af[m], bfr[n], acc[m][n]);
        }
    }
    for (int m = 0; m < 4; ++m)
        for (int n = 0; n < 4; ++n) {
            int row = bm * 128 + wr * 64 + m * 16 + ((lane >> 4) << 2);
            int col = bn * 128 + wc * 64 + n * 16 + (lane & 15);
            float bv_ = bias[col];
            for (int i = 0; i < 4; ++i)
                O[(size_t)(row + i) * N + col] = acc[m][n][i] + bv_;
        }
}

// ---------------------------------------------------------------------------
// Flash attention v9 SLIM: single-tile loop, KV split across blocks (z=0/1),
// targeting <=64 VGPR (the measured occupancy threshold: 64->2x blocks/CU).
// __launch_bounds__(256,4) => empirical cap 64. Peak-live budget ~62:
// qf 8 + oacc 16 + s 16 (exp2 done IN PLACE, packed per-kb so dead halves
// free regs before V-fragment loads) + prefetch 16 + addr ~6.
// Spill canary: WRITE_SIZE (must stay ~8.7 MB).
// ---------------------------------------------------------------------------
__global__ __launch_bounds__(256, 4) void attn_k(
    const u16* __restrict__ Qp, const u16* __restrict__ Kp, const u16* __restrict__ Vp,
    const unsigned char* __restrict__ mask,
    u16* __restrict__ Op0, u16* __restrict__ Op1,
    float2* __restrict__ ml0, float2* __restrict__ ml1)
{
    constexpr int C = 512, NK = 2048, KVH = 1024, NT = KVH / 64;   // 16 tiles
    __shared__ u16 lK[64 * 64];
    __shared__ u16 lV[64 * 64];

    const int tid = threadIdx.x, lane = tid & 63, w = tid >> 6;
    const int gd = lane >> 4, q15 = lane & 15;
    const int bh = blockIdx.x, qb = blockIdx.y, z = blockIdx.z;
    const int b = bh >> 3, h = bh & 7;
    const size_t qrow0 = (size_t)b * 2048 + qb * 64;
    const size_t krow0 = (size_t)b * 2048 + (size_t)z * KVH;
    const int col0 = h * 64;
    const int rs = tid >> 3, cc = tid & 7;   // rs 0..31

    u16* __restrict__ Op = z ? Op1 : Op0;
    float2* __restrict__ ml = z ? ml1 : ml0;

    // Q fragments in registers (B-operand): lane holds Q[q15][kb*32+gd*8 ..+8]
    bf16x8 qf[2];
    {
        const u16* qrow = Qp + (qrow0 + w * 16 + q15) * C + col0;
        qf[0] = *(const bf16x8*)(qrow + gd * 8);
        qf[1] = *(const bf16x8*)(qrow + 32 + gd * 8);
    }

    float mst = -1e30f, lstp = 0.f;
    f32x4 oacc[4];
    #pragma unroll
    for (int i = 0; i < 4; ++i) oacc[i] = f32x4{0.f, 0.f, 0.f, 0.f};

    // prefetch tile 0 (rows rs and rs+32)
    short8 kpre[2], vpre[2];
    #pragma unroll
    for (int p = 0; p < 2; ++p) {
        kpre[p] = *(const short8*)(Kp + (krow0 + rs + p * 32) * C + col0 + cc * 8);
        vpre[p] = *(const short8*)(Vp + (krow0 + rs + p * 32) * C + col0 + cc * 8);
    }

    for (int t = 0; t < NT; ++t) {
        __syncthreads();   // previous compute done; safe to overwrite LDS
        #pragma unroll
        for (int p = 0; p < 2; ++p) {
            int r = rs + p * 32;
            *(short8*)&lK[r * 64 + ((cc ^ (r & 7)) << 3)] = kpre[p];
            #pragma unroll
            for (int j = 0; j < 8; ++j)
                lV[(cc * 8 + j) * 64 + (((r >> 3) ^ ((j + cc) & 7)) << 3) + (r & 7)] = (u16)vpre[p][j];
        }
        if (t + 1 < NT) {
            #pragma unroll
            for (int p = 0; p < 2; ++p) {
                kpre[p] = *(const short8*)(Kp + (krow0 + (t + 1) * 64 + rs + p * 32) * C + col0 + cc * 8);
                vpre[p] = *(const short8*)(Vp + (krow0 + (t + 1) * 64 + rs + p * 32) * C + col0 + cc * 8);
            }
        }
        __syncthreads();   // staging visible

        unsigned char mby = mask[(size_t)b * NK + z * KVH + t * 64 + lane];

        // QK^T swapped: lane holds S^T[16*t4+4*gd+i][q15]
        f32x4 s[4];
        #pragma unroll
        for (int i = 0; i < 4; ++i) s[i] = f32x4{0.f, 0.f, 0.f, 0.f};
        __builtin_amdgcn_s_setprio(1);
        #pragma unroll
        for (int kb = 0; kb < 2; ++kb)
            #pragma unroll
            for (int t4 = 0; t4 < 4; ++t4) {
                int krow = t4 * 16 + q15;
                bf16x8 kf = *(const bf16x8*)&lK[krow * 64 + (((kb * 4 + gd) ^ (krow & 7)) << 3)];
                s[t4] = MFMA_BF16(kf, qf[kb], s[t4]);
            }
        __builtin_amdgcn_s_setprio(0);

        // key-padding mask (uniform branch; all-false for this input)
        unsigned long long m64 = __ballot(mby != 0);
        if (m64) {
            #pragma unroll
            for (int t4 = 0; t4 < 4; ++t4)
                #pragma unroll
                for (int i = 0; i < 4; ++i) {
                    int k = t4 * 16 + gd * 4 + i;
                    if ((m64 >> k) & 1ull) s[t4][i] = -1e30f;
                }
        }

        // lane-local max; defer-max check needs no cross-lane reduce
        float pmax = s[0][0];
        #pragma unroll
        for (int t4 = 0; t4 < 4; ++t4)
            #pragma unroll
            for (int i = 0; i < 4; ++i) pmax = fmaxf(pmax, s[t4][i]);

        if (!__all(pmax - mst <= 11.0f)) {
            float rm = fmaxf(pmax, __shfl_xor(pmax, 16));
            rm = fmaxf(rm, __shfl_xor(rm, 32));
            float mn = fmaxf(mst, rm);
            float sf = exp2f(mst - mn);
            mst = mn;
            lstp *= sf;
            #pragma unroll
            for (int i = 0; i < 4; ++i) {
                float sfi = __shfl(sf, (lane & 48) | ((gd << 2) + i));
                #pragma unroll
                for (int t2 = 0; t2 < 4; ++t2) oacc[t2][i] *= sfi;
            }
        }

        // exp2 IN PLACE over s, accumulate row-sum partial
        float rsum = 0.f;
        #pragma unroll
        for (int t4 = 0; t4 < 4; ++t4)
            #pragma unroll
            for (int i = 0; i < 4; ++i) {
                float e = fast_exp2(s[t4][i] - mst);
                s[t4][i] = e;
                rsum += e;
            }
        lstp += rsum;

        // PV per-kb: pack from s (dead after pack), then 4 MFMA with V frags
        __builtin_amdgcn_s_setprio(1);
        #pragma unroll
        for (int kb = 0; kb < 2; ++kb) {
            u32x4 pw;
            pw[0] = cvt_pk_bf16(s[2 * kb][0], s[2 * kb][1]);
            pw[1] = cvt_pk_bf16(s[2 * kb][2], s[2 * kb][3]);
            pw[2] = cvt_pk_bf16(s[2 * kb + 1][0], s[2 * kb + 1][1]);
            pw[3] = cvt_pk_bf16(s[2 * kb + 1][2], s[2 * kb + 1][3]);
            bf16x8 pa = __builtin_bit_cast(bf16x8, pw);
            #pragma unroll
            for (int t2 = 0; t2 < 4; ++t2) {
                int d = t2 * 16 + q15;
                int swd = (d + (d >> 3)) & 7;
                int base = d * 64 + 4 * (gd & 1);
                uint2 v0 = *(const uint2*)&lV[base + (((4 * kb + 0 + (gd >> 1)) ^ swd) << 3)];
                uint2 v1 = *(const uint2*)&lV[base + (((4 * kb + 2 + (gd >> 1)) ^ swd) << 3)];
                u32x4 vw; vw[0] = v0.x; vw[1] = v0.y; vw[2] = v1.x; vw[3] = v1.y;
                bf16x8 vf = __builtin_bit_cast(bf16x8, vw);
                oacc[t2] = MFMA_BF16(pa, vf, oacc[t2]);
            }
        }
        __builtin_amdgcn_s_setprio(0);
    }

    // row-reduce partial sums (lanes sharing q15 across gd groups)
    float lsum = lstp + __shfl_xor(lstp, 16);
    lsum += __shfl_xor(lsum, 32);

    // per-row (m, l) for the merge (one writer per row)
    if (gd == 0)
        ml[bh * 2048 + qb * 64 + w * 16 + q15] = make_float2(mst, lsum);

    // normalized partial O
    #pragma unroll
    for (int i = 0; i < 4; ++i) {
        float li = __shfl(lsum, (lane & 48) | ((gd << 2) + i));
        float inv = 1.f / li;
        int qg = qb * 64 + w * 16 + gd * 4 + i;
        #pragma unroll
        for (int t2 = 0; t2 < 4; ++t2) {
            int col = col0 + t2 * 16 + q15;
            Op[((size_t)b * 2048 + qg) * C + col] = f2bf(oacc[t2][i] * inv);
        }
    }
}

extern "C" void kernel_launch(void* const* d_in, const int* in_sizes, int n_in,
                              void* d_out, int out_size, void* d_ws, size_t ws_size,
                              hipStream_t stream) {
    const float* query = (const float*)d_in[0];
    const float* key   = (const float*)d_in[1];
    const float* value = (const float*)d_in[2];
    const unsigned char* mask = (const unsigned char*)d_in[3];
    const float* Wq = (const float*)d_in[4];
    const float* bq = (const float*)d_in[5];
    const float* Wk = (const float*)d_in[6];
    const float* bk = (const float*)d_in[7];
    const float* Wv = (const float*)d_in[8];
    const float* bv = (const float*)d_in[9];
    const float* Wo = (const float*)d_in[10];
    const float* bo = (const float*)d_in[11];

    // ws layout (u16 elems): Qp|Kp|Vp|Op0|Op1 (2M each), ml0|ml1 (256 KB each).
    // Ob (merged) overlays Qp: attn finishes reading Qp before merge_k runs
    // (same-stream ordering), and proj_gemm rewrites Qp every call.
    u16* ws = (u16*)d_ws;
    u16* Qp  = ws;
    u16* Kp  = ws + 2097152;
    u16* Vp  = ws + 4194304;
    u16* Op0 = ws + 6291456;
    u16* Op1 = ws + 8388608;
    float2* ml0 = (float2*)(ws + 10485760);
    float2* ml1 = (float2*)(ws + 10485760 + 131072);
    u16* Ob = Qp;

    dim3 gp(32, 4, 3);
    proj_gemm<<<gp, 256, 0, stream>>>(query, key, value, Wq, Wk, Wv, bq, bk, bv, Qp, Kp, Vp);

    dim3 ga(16, 32, 2);   // x = bh (XCD locality), y = q-tile, z = KV half
    attn_k<<<ga, 256, 0, stream>>>(Qp, Kp, Vp, mask, Op0, Op1, ml0, ml1);

    merge_k<<<1024, 256, 0, stream>>>(Op0, Op1, ml0, ml1, Ob);

    dim3 go(32, 4);
    out_gemm<<<go, 256, 0, stream>>>(Ob, Wo, bo, (float*)d_out);
}